// Round 7
// baseline (210.549 us; speedup 1.0000x reference)
//
#include <hip/hip_runtime.h>
#include <hip/hip_bf16.h>
#include <math.h>

// PairwiseCosineSimilarity: C[n][m] = <x1[n],x2[m]> / (max(||x1||,eps)*max(||x2||,eps))
// Round 7: normalize rows -> bf16, then 256x256-tile MFMA GEMM.
// 4-phase/K-tile pipeline with TWO-K-TILE-DEEP prefetch:
//   - slabs B0-3,A0,A2 of a buffer die after phase 3 -> phase 4 restages them
//     for tile kt+2 (same parity); A1,A3 die after phase 4 -> restaged at
//     ph1 of the next iteration.
//   - two vmcnt(8) waits per K-tile; every load gets 4-5 phases (>1200 cyc)
//     of flight; queue never drains below 8.
// Zero-conflict XOR-swizzled LDS (pre-swizzled global source + swizzled read),
// setprio around MFMA, XCD-aware block swizzle, plain C stores (NT reverted:
// it caused +15% write amplification in round 6).

typedef __bf16 bf16x8 __attribute__((ext_vector_type(8)));
typedef float  f32x4  __attribute__((ext_vector_type(4)));

#define LDSP(x) ((__attribute__((address_space(3))) void*)(x))
#define GLBP(x) ((const __attribute__((address_space(1))) void*)(x))

#define BM 256
#define BN 256
#define BK 64
#define EPS_CS 1e-8f

// ---------------- normalize: one block per row, D == 1024 ----------------

__global__ __launch_bounds__(256) void nrm_bf16_1024(const float* __restrict__ in,
                                                     __bf16* __restrict__ out) {
    const int row = blockIdx.x;
    const int t = threadIdx.x;
    const float4 v = reinterpret_cast<const float4*>(in + (size_t)row * 1024)[t];
    float ss = v.x * v.x + v.y * v.y + v.z * v.z + v.w * v.w;
#pragma unroll
    for (int off = 32; off > 0; off >>= 1) ss += __shfl_down(ss, off, 64);
    __shared__ float red[4];
    const int lane = t & 63, wid = t >> 6;
    if (lane == 0) red[wid] = ss;
    __syncthreads();
    const float tot = red[0] + red[1] + red[2] + red[3];
    const float rn = 1.0f / fmaxf(sqrtf(tot), EPS_CS);
    ushort4 pk;
    pk.x = __builtin_bit_cast(unsigned short, (__bf16)(v.x * rn));
    pk.y = __builtin_bit_cast(unsigned short, (__bf16)(v.y * rn));
    pk.z = __builtin_bit_cast(unsigned short, (__bf16)(v.z * rn));
    pk.w = __builtin_bit_cast(unsigned short, (__bf16)(v.w * rn));
    reinterpret_cast<ushort4*>(out + (size_t)row * 1024)[t] = pk;
}

// ---------------- 256x256 pipelined MFMA GEMM:  C = A * B^T ----------------
// A[NR][D], B[NC][D] bf16 row-major; C[NR][NC] f32. NR,NC % 256 == 0,
// D % 64 == 0, D >= 128. Grid = (NR/256)*(NC/256), block = 512 (8 waves, 2x4).
// Per wave: 128x64 output, acc[8][4] f32x4. LDS: 2 x (A 256x64 + B 256x64) = 128 KB.
//
// Slab = 64 rows x 64 k of A or B (one gload_lds x16B per thread).
// Wave (wm,wn) reads A slabs {2wm, 2wm+1} and B slab {wn}.
// Consumption: ph1 g0{B,A-even}, ph2 g0{A-odd}, ph3 g1{B,A-even}, ph4 g1{A-odd}.
// Staging (iteration kt): ph1 -> A1,A3 of tile kt+1 (buf nb);
//                         ph4 -> B0-3,A0,A2 of tile kt+2 (buf cur; those slabs
//                                died at ph3's closing barrier).
// Per-thread VM queue entering iteration kt: [A1A3(kt)] [6(kt+1)] = 8.
//   end-ph1: +2(A1A3 kt+1) = 10 -> vmcnt(8) retires A1A3(kt)  [4-phase flight]
//   end-ph4: +6(kt+2)      = 14 -> vmcnt(8) retires 6(kt+1)   [4-5 phase flight]

__global__ __launch_bounds__(512, 2) void gemm_nt_bf16_256(const __bf16* __restrict__ A,
                                                           const __bf16* __restrict__ B,
                                                           float* __restrict__ C,
                                                           int NC, int D) {
    __shared__ __bf16 As[2][BM * BK];   // 2 x 32 KB
    __shared__ __bf16 Bs[2][BN * BK];   // 2 x 32 KB

    const int t    = threadIdx.x;
    const int lane = t & 63;
    const int wid  = t >> 6;            // 0..7
    const int wm   = wid >> 2;          // 0..1  (128-row strip)
    const int wn   = wid & 3;           // 0..3  (64-col strip)
    const int fr   = lane & 15;         // fragment row/col
    const int fq   = lane >> 4;         // 0..3  (k sub-group)
    const int xk   = fr & 7;            // read XOR key == (row & 7)
    const int g0   = fq ^ xk;           // kh=0 physical 16B-group
    const int g1   = (4 + fq) ^ xk;     // kh=1 physical 16B-group

    // XCD-aware bijective block swizzle (grid % 8 == 0 on the fast path)
    const int nwg = gridDim.x;
    int swz = blockIdx.x;
    if ((nwg & 7) == 0) swz = (swz & 7) * (nwg >> 3) + (swz >> 3);
    const int ntn  = NC / BN;
    const int brow = (swz / ntn) * BM;
    const int bcol = (swz % ntn) * BN;

    // staging: thread t covers LDS elements [t*8, t*8+8) of a 64-row slab.
    // LDS row-in-slab = t>>3, physical group = t&7; source k-group is
    // pre-swizzled: (t&7) ^ (row&7)  (inverse of the read XOR).
    const int srow = t >> 3;                         // 0..63
    const int sg8  = ((t & 7) ^ (srow & 7)) << 3;    // swizzled k element offset
    const __bf16* aSrc = A + (size_t)(brow + srow) * D + sg8;
    const __bf16* bSrc = B + (size_t)(bcol + srow) * D + sg8;
    const int ldsOff = t * 8;

    auto stageA = [&](int buf, int slab, int k) {
        __builtin_amdgcn_global_load_lds(GLBP(aSrc + (size_t)slab * 64 * D + k),
                                         LDSP(&As[buf][slab * 4096 + ldsOff]), 16, 0, 0);
    };
    auto stageB = [&](int buf, int slab, int k) {
        __builtin_amdgcn_global_load_lds(GLBP(bSrc + (size_t)slab * 64 * D + k),
                                         LDSP(&Bs[buf][slab * 4096 + ldsOff]), 16, 0, 0);
    };
    auto ldA = [&](int buf, int mh, int m, int g) {
        const int row = wm * 128 + mh * 64 + m * 16 + fr;
        return *reinterpret_cast<const bf16x8*>(&As[buf][row * 64 + g * 8]);
    };
    auto ldB = [&](int buf, int n, int g) {
        const int row = wn * 64 + n * 16 + fr;
        return *reinterpret_cast<const bf16x8*>(&Bs[buf][row * 64 + g * 8]);
    };

    f32x4 acc[8][4];
#pragma unroll
    for (int i = 0; i < 8; ++i)
#pragma unroll
        for (int n = 0; n < 4; ++n)
            acc[i][n] = (f32x4){0.f, 0.f, 0.f, 0.f};

    // ---- prologue: issue t0's 6, t0's A1A3, t1's 6; retire t0's 6 ----
    stageB(0, 0, 0); stageB(0, 1, 0); stageB(0, 2, 0); stageB(0, 3, 0);
    stageA(0, 0, 0); stageA(0, 2, 0);
    stageA(0, 1, 0); stageA(0, 3, 0);
    stageB(1, 0, BK); stageB(1, 1, BK); stageB(1, 2, BK); stageB(1, 3, BK);
    stageA(1, 0, BK); stageA(1, 2, BK);
    asm volatile("s_waitcnt vmcnt(8)" ::: "memory");
    __builtin_amdgcn_s_barrier();

    const int NT = D / BK;   // >= 2 on the fast path
    int cur = 0;
    for (int kt = 0; kt < NT; ++kt) {
        const int nb = cur ^ 1;
        // dummy re-stages of tile 0 beyond the end keep vmcnt counts uniform;
        // they write only dead slabs (same disjointness as the real schedule).
        const int kA = (kt + 1 < NT ? kt + 1 : 0) * BK;  // A1,A3 of tile kt+1 -> nb
        const int kN = (kt + 2 < NT ? 0 : 0) + (kt + 2 < NT ? (kt + 2) * BK : 0); // 6 of kt+2 -> cur
        bf16x8 a[4], b[4];

        // ======== phase 1: kh=0, mh=0 ========
#pragma unroll
        for (int n = 0; n < 4; ++n) b[n] = ldB(cur, n, g0);
#pragma unroll
        for (int m = 0; m < 4; ++m) a[m] = ldA(cur, 0, m, g0);
        stageA(nb, 1, kA); stageA(nb, 3, kA);
        __builtin_amdgcn_s_barrier();
        __builtin_amdgcn_s_setprio(1);
#pragma unroll
        for (int m = 0; m < 4; ++m)
#pragma unroll
            for (int n = 0; n < 4; ++n)
                acc[m][n] = __builtin_amdgcn_mfma_f32_16x16x32_bf16(a[m], b[n], acc[m][n], 0, 0, 0);
        __builtin_amdgcn_s_setprio(0);
        // retire A1,A3 of cur tile (issued iteration kt-1 ph1: 4 phases in flight)
        asm volatile("s_waitcnt vmcnt(8)" ::: "memory");
        __builtin_amdgcn_s_barrier();

        // ======== phase 2: kh=0, mh=1 (reuse b) ========
#pragma unroll
        for (int m = 0; m < 4; ++m) a[m] = ldA(cur, 1, m, g0);
        __builtin_amdgcn_s_barrier();
        __builtin_amdgcn_s_setprio(1);
#pragma unroll
        for (int m = 0; m < 4; ++m)
#pragma unroll
            for (int n = 0; n < 4; ++n)
                acc[4 + m][n] = __builtin_amdgcn_mfma_f32_16x16x32_bf16(a[m], b[n], acc[4 + m][n], 0, 0, 0);
        __builtin_amdgcn_s_setprio(0);
        __builtin_amdgcn_s_barrier();

        // ======== phase 3: kh=1, mh=0 ========
#pragma unroll
        for (int n = 0; n < 4; ++n) b[n] = ldB(cur, n, g1);
#pragma unroll
        for (int m = 0; m < 4; ++m) a[m] = ldA(cur, 0, m, g1);
        __builtin_amdgcn_s_barrier();
        __builtin_amdgcn_s_setprio(1);
#pragma unroll
        for (int m = 0; m < 4; ++m)
#pragma unroll
            for (int n = 0; n < 4; ++n)
                acc[m][n] = __builtin_amdgcn_mfma_f32_16x16x32_bf16(a[m], b[n], acc[m][n], 0, 0, 0);
        __builtin_amdgcn_s_setprio(0);
        __builtin_amdgcn_s_barrier();
        // after this barrier, slabs B0-3,A0,A2 of buf cur are dead (last read: g1 above)

        // ======== phase 4: kh=1, mh=1 ========
#pragma unroll
        for (int m = 0; m < 4; ++m) a[m] = ldA(cur, 1, m, g1);
        stageB(cur, 0, kN); stageB(cur, 1, kN); stageB(cur, 2, kN); stageB(cur, 3, kN);
        stageA(cur, 0, kN); stageA(cur, 2, kN);
        __builtin_amdgcn_s_barrier();
        __builtin_amdgcn_s_setprio(1);
#pragma unroll
        for (int m = 0; m < 4; ++m)
#pragma unroll
            for (int n = 0; n < 4; ++n)
                acc[4 + m][n] = __builtin_amdgcn_mfma_f32_16x16x32_bf16(a[m], b[n], acc[4 + m][n], 0, 0, 0);
        __builtin_amdgcn_s_setprio(0);
        // retire B0-3,A0,A2 of tile kt+1 (issued iteration kt-1 ph4: 4-5 phases in flight)
        asm volatile("s_waitcnt vmcnt(8)" ::: "memory");
        __builtin_amdgcn_s_barrier();

        cur = nb;
    }
    asm volatile("s_waitcnt vmcnt(0)" ::: "memory");  // drain dummy stages

    // ---- epilogue: D[row][col], col = lane&15, row = (lane>>4)*4 + reg ----
    const int crow0 = brow + wm * 128;
    const int ccol0 = bcol + wn * 64;
    const int rr    = fq * 4;
#pragma unroll
    for (int mh = 0; mh < 2; ++mh) {
#pragma unroll
        for (int m = 0; m < 4; ++m) {
#pragma unroll
            for (int r = 0; r < 4; ++r) {
                const size_t rowoff = (size_t)(crow0 + mh * 64 + m * 16 + rr + r) * NC;
#pragma unroll
                for (int n = 0; n < 4; ++n)
                    C[rowoff + ccol0 + n * 16 + fr] = acc[mh * 4 + m][n][r];
            }
        }
    }
}

// ---------------- fallback path (odd shapes / tiny ws) ----------------

__global__ __launch_bounds__(256) void rnorm_rows(const float* __restrict__ in,
                                                  float* __restrict__ rn, int D) {
    const int row = blockIdx.x;
    float ss = 0.f;
    for (int c = threadIdx.x; c < D; c += 256) {
        const float v = in[(size_t)row * D + c];
        ss += v * v;
    }
#pragma unroll
    for (int off = 32; off > 0; off >>= 1) ss += __shfl_down(ss, off, 64);
    __shared__ float red[4];
    if ((threadIdx.x & 63) == 0) red[threadIdx.x >> 6] = ss;
    __syncthreads();
    if (threadIdx.x == 0) {
        const float tot = red[0] + red[1] + red[2] + red[3];
        rn[row] = 1.0f / fmaxf(sqrtf(tot), EPS_CS);
    }
}

__global__ __launch_bounds__(256) void gemm_f32_fallback(const float* __restrict__ x1,
                                                         const float* __restrict__ x2,
                                                         const float* __restrict__ rn1,
                                                         const float* __restrict__ rn2,
                                                         float* __restrict__ C,
                                                         int NR, int NC, int D) {
    __shared__ float a[16][17], b[16][17];
    const int tx = threadIdx.x & 15, ty = threadIdx.x >> 4;
    const int row = blockIdx.y * 16 + ty;
    const int colb = blockIdx.x * 16;
    float acc = 0.f;
    for (int k0 = 0; k0 < D; k0 += 16) {
        a[ty][tx] = (row < NR && k0 + tx < D) ? x1[(size_t)row * D + k0 + tx] : 0.f;
        b[ty][tx] = (colb + ty < NC && k0 + tx < D) ? x2[(size_t)(colb + ty) * D + k0 + tx] : 0.f;
        __syncthreads();
#pragma unroll
        for (int k = 0; k < 16; ++k) acc += a[ty][k] * b[tx][k];
        __syncthreads();
    }
    if (row < NR && colb + tx < NC)
        C[(size_t)row * NC + colb + tx] = acc * rn1[row] * rn2[colb + tx];
}

// ---------------- launch ----------------

extern "C" void kernel_launch(void* const* d_in, const int* in_sizes, int n_in,
                              void* d_out, int out_size, void* d_ws, size_t ws_size,
                              hipStream_t stream) {
    const float* x1 = (const float*)d_in[0];
    const float* x2 = (const float*)d_in[1];
    float* C = (float*)d_out;

    const int D  = 1024;
    const int NR = in_sizes[0] / D;
    const int NC = in_sizes[1] / D;

    const size_t need = ((size_t)NR + (size_t)NC) * (size_t)D * sizeof(__bf16);
    const bool fast = (in_sizes[0] % D == 0) && (in_sizes[1] % D == 0) &&
                      (NR % BM == 0) && (NC % BN == 0) && (D / BK >= 2) &&
                      (ws_size >= need);

    if (fast) {
        __bf16* An = (__bf16*)d_ws;
        __bf16* Bn = An + (size_t)NR * D;
        nrm_bf16_1024<<<NR, 256, 0, stream>>>(x1, An);
        nrm_bf16_1024<<<NC, 256, 0, stream>>>(x2, Bn);
        const int grid = (NR / BM) * (NC / BN);
        gemm_nt_bf16_256<<<grid, 512, 0, stream>>>(An, Bn, C, NC, D);
    } else {
        float* rn1 = (float*)d_ws;
        float* rn2 = rn1 + NR;
        rnorm_rows<<<NR, 256, 0, stream>>>(x1, rn1, D);
        rnorm_rows<<<NC, 256, 0, stream>>>(x2, rn2, D);
        dim3 g((NC + 15) / 16, (NR + 15) / 16);
        gemm_f32_fallback<<<g, 256, 0, stream>>>(x1, x2, rn1, rn2, C, NR, NC, D);
    }
}

// Round 8
// 196.112 us; speedup vs baseline: 1.0736x; 1.0736x over previous
//
#include <hip/hip_runtime.h>
#include <hip/hip_bf16.h>
#include <math.h>

// PairwiseCosineSimilarity: C[n][m] = <x1[n],x2[m]> / (max(||x1||,eps)*max(||x2||,eps))
// Round 8: normalize rows -> bf16, then 256x256-tile MFMA GEMM.
// Round-5 4-phase skeleton + REGISTER READ-AHEAD: phase p issues the ds_reads
// for phase p+1's MFMA, so LDS drain overlaps MFMA execution (they're
// register-independent). One barrier per phase (read-completion is enforced
// by the lgkmcnt before the NEXT phase's MFMA, which precedes that phase's
// closing barrier -> write-after-read safe).
//
// Schedule (tile t, buf p=t&1, q=p^1); reads serve the NEXT phase's MFMA:
//   P1: read a_odd_g0[t]<-p   | stage A1,A3[t+1]->q    | MFMA mh0*g0 (ae0,bg0)
//   P2: read bg1,ae1[t]<-p    |                        | MFMA mh1*g0 (ao0,bg0)
//   P3: read a_odd_g1[t]<-p   | vmcnt(2)               | MFMA mh0*g1 (ae1,bg1)
//   P4: read bg0,ae0[t+1]<-q  | stage B0-3,A0,A2[t+2]->p, vmcnt(6) | MFMA mh1*g1
// Per-thread VM queue: P1 +2, P4 +6; vmcnt(2)@P3 retires the 6-batch (3-phase
// flight), vmcnt(6)@P4 retires the A-odd pair (3-phase flight). Never drains.
// Zero-conflict XOR-swizzled LDS (pre-swizzled global source + swizzled read),
// XCD-aware block swizzle, plain C stores.

typedef __bf16 bf16x8 __attribute__((ext_vector_type(8)));
typedef float  f32x4  __attribute__((ext_vector_type(4)));

#define LDSP(x) ((__attribute__((address_space(3))) void*)(x))
#define GLBP(x) ((const __attribute__((address_space(1))) void*)(x))

#define BM 256
#define BN 256
#define BK 64
#define EPS_CS 1e-8f

// ---------------- normalize: one block per row, D == 1024 ----------------

__global__ __launch_bounds__(256) void nrm_bf16_1024(const float* __restrict__ in,
                                                     __bf16* __restrict__ out) {
    const int row = blockIdx.x;
    const int t = threadIdx.x;
    const float4 v = reinterpret_cast<const float4*>(in + (size_t)row * 1024)[t];
    float ss = v.x * v.x + v.y * v.y + v.z * v.z + v.w * v.w;
#pragma unroll
    for (int off = 32; off > 0; off >>= 1) ss += __shfl_down(ss, off, 64);
    __shared__ float red[4];
    const int lane = t & 63, wid = t >> 6;
    if (lane == 0) red[wid] = ss;
    __syncthreads();
    const float tot = red[0] + red[1] + red[2] + red[3];
    const float rn = 1.0f / fmaxf(sqrtf(tot), EPS_CS);
    ushort4 pk;
    pk.x = __builtin_bit_cast(unsigned short, (__bf16)(v.x * rn));
    pk.y = __builtin_bit_cast(unsigned short, (__bf16)(v.y * rn));
    pk.z = __builtin_bit_cast(unsigned short, (__bf16)(v.z * rn));
    pk.w = __builtin_bit_cast(unsigned short, (__bf16)(v.w * rn));
    reinterpret_cast<ushort4*>(out + (size_t)row * 1024)[t] = pk;
}

// ---------------- 256x256 pipelined MFMA GEMM:  C = A * B^T ----------------

__global__ __launch_bounds__(512, 2) void gemm_nt_bf16_256(const __bf16* __restrict__ A,
                                                           const __bf16* __restrict__ B,
                                                           float* __restrict__ C,
                                                           int NC, int D) {
    __shared__ __bf16 As[2][BM * BK];   // 2 x 32 KB
    __shared__ __bf16 Bs[2][BN * BK];   // 2 x 32 KB

    const int t    = threadIdx.x;
    const int lane = t & 63;
    const int wid  = t >> 6;            // 0..7
    const int wm   = wid >> 2;          // 0..1  (128-row strip)
    const int wn   = wid & 3;           // 0..3  (64-col strip)
    const int fr   = lane & 15;         // fragment row/col
    const int fq   = lane >> 4;         // 0..3  (k sub-group)
    const int xk   = fr & 7;            // read XOR key == (row & 7)
    const int g0   = fq ^ xk;           // kh=0 physical 16B-group
    const int g1   = (4 + fq) ^ xk;     // kh=1 physical 16B-group

    // XCD-aware bijective block swizzle (grid % 8 == 0 on the fast path)
    const int nwg = gridDim.x;
    int swz = blockIdx.x;
    if ((nwg & 7) == 0) swz = (swz & 7) * (nwg >> 3) + (swz >> 3);
    const int ntn  = NC / BN;
    const int brow = (swz / ntn) * BM;
    const int bcol = (swz % ntn) * BN;

    // staging: thread t covers LDS elements [t*8, t*8+8) of a 64-row slab.
    // source k-group pre-swizzled: (t&7) ^ (row&7) (inverse of the read XOR).
    const int srow = t >> 3;                         // 0..63
    const int sg8  = ((t & 7) ^ (srow & 7)) << 3;
    const __bf16* aSrc = A + (size_t)(brow + srow) * D + sg8;
    const __bf16* bSrc = B + (size_t)(bcol + srow) * D + sg8;
    const int ldsOff = t * 8;

    auto stageA = [&](int buf, int slab, int k) {
        __builtin_amdgcn_global_load_lds(GLBP(aSrc + (size_t)slab * 64 * D + k),
                                         LDSP(&As[buf][slab * 4096 + ldsOff]), 16, 0, 0);
    };
    auto stageB = [&](int buf, int slab, int k) {
        __builtin_amdgcn_global_load_lds(GLBP(bSrc + (size_t)slab * 64 * D + k),
                                         LDSP(&Bs[buf][slab * 4096 + ldsOff]), 16, 0, 0);
    };
    auto ldA = [&](int buf, int mh, int m, int g) {
        const int row = wm * 128 + mh * 64 + m * 16 + fr;
        return *reinterpret_cast<const bf16x8*>(&As[buf][row * 64 + g * 8]);
    };
    auto ldB = [&](int buf, int n, int g) {
        const int row = wn * 64 + n * 16 + fr;
        return *reinterpret_cast<const bf16x8*>(&Bs[buf][row * 64 + g * 8]);
    };

    f32x4 acc[8][4];
#pragma unroll
    for (int i = 0; i < 8; ++i)
#pragma unroll
        for (int n = 0; n < 4; ++n)
            acc[i][n] = (f32x4){0.f, 0.f, 0.f, 0.f};

    bf16x8 bg0[4], ae0[4], ao0[4], bg1[4], ae1[4], ao1[4];

    // ---- prologue ----
    stageB(0, 0, 0); stageB(0, 1, 0); stageB(0, 2, 0); stageB(0, 3, 0);
    stageA(0, 0, 0); stageA(0, 2, 0);                  // 6: B,A-even of tile 0
    stageA(0, 1, 0); stageA(0, 3, 0);                  // 2: A-odd of tile 0
    asm volatile("s_waitcnt vmcnt(2)" ::: "memory");   // retire the 6
    __builtin_amdgcn_s_barrier();
#pragma unroll
    for (int n = 0; n < 4; ++n) bg0[n] = ldB(0, n, g0);
#pragma unroll
    for (int m = 0; m < 4; ++m) ae0[m] = ldA(0, 0, m, g0);
    stageB(1, 0, BK); stageB(1, 1, BK); stageB(1, 2, BK); stageB(1, 3, BK);
    stageA(1, 0, BK); stageA(1, 2, BK);                // 6: B,A-even of tile 1
    asm volatile("s_waitcnt vmcnt(6)" ::: "memory");   // retire A-odd of tile 0
    __builtin_amdgcn_s_barrier();
    // entering loop: outstanding = 6 (B,A-even of tile 1)

    const int NT = D / BK;   // >= 2 on the fast path
    for (int kt = 0; kt < NT; ++kt) {
        const int p = kt & 1, q = p ^ 1;
        const int kA1 = (kt + 1 < NT ? kt + 1 : 0) * BK;  // A-odd of t+1 -> buf q
        const int kS  = (kt + 2 < NT ? kt + 2 : 0) * BK;  // 6-batch of t+2 -> buf p
        // (wrapped k=0 re-stages are dummies into dead slabs; never read,
        //  keep vmcnt counts uniform)

        // ======== P1: MFMA mh0*g0 | read a_odd_g0[t] | stage A-odd[t+1] ========
#pragma unroll
        for (int m = 0; m < 4; ++m) ao0[m] = ldA(p, 1, m, g0);
        stageA(q, 1, kA1); stageA(q, 3, kA1);
        __builtin_amdgcn_s_setprio(1);
#pragma unroll
        for (int m = 0; m < 4; ++m)
#pragma unroll
            for (int n = 0; n < 4; ++n)
                acc[m][n] = __builtin_amdgcn_mfma_f32_16x16x32_bf16(ae0[m], bg0[n], acc[m][n], 0, 0, 0);
        __builtin_amdgcn_s_setprio(0);
        __builtin_amdgcn_s_barrier();

        // ======== P2: MFMA mh1*g0 | read bg1, ae1 [t] ========
#pragma unroll
        for (int n = 0; n < 4; ++n) bg1[n] = ldB(p, n, g1);
#pragma unroll
        for (int m = 0; m < 4; ++m) ae1[m] = ldA(p, 0, m, g1);
        __builtin_amdgcn_s_setprio(1);
#pragma unroll
        for (int m = 0; m < 4; ++m)
#pragma unroll
            for (int n = 0; n < 4; ++n)
                acc[4 + m][n] = __builtin_amdgcn_mfma_f32_16x16x32_bf16(ao0[m], bg0[n], acc[4 + m][n], 0, 0, 0);
        __builtin_amdgcn_s_setprio(0);
        __builtin_amdgcn_s_barrier();

        // ======== P3: MFMA mh0*g1 | read a_odd_g1[t] | vmcnt(2) ========
#pragma unroll
        for (int m = 0; m < 4; ++m) ao1[m] = ldA(p, 1, m, g1);
        __builtin_amdgcn_s_setprio(1);
#pragma unroll
        for (int m = 0; m < 4; ++m)
#pragma unroll
            for (int n = 0; n < 4; ++n)
                acc[m][n] = __builtin_amdgcn_mfma_f32_16x16x32_bf16(ae1[m], bg1[n], acc[m][n], 0, 0, 0);
        __builtin_amdgcn_s_setprio(0);
        // retire B,A-even of tile t+1 (staged P4 of t-1: 3-phase flight)
        asm volatile("s_waitcnt vmcnt(2)" ::: "memory");
        __builtin_amdgcn_s_barrier();

        // ======== P4: MFMA mh1*g1 | read bg0, ae0 of t+1 <- buf q | stage 6[t+2] ========
#pragma unroll
        for (int n = 0; n < 4; ++n) bg0[n] = ldB(q, n, g0);
#pragma unroll
        for (int m = 0; m < 4; ++m) ae0[m] = ldA(q, 0, m, g0);
        stageB(p, 0, kS); stageB(p, 1, kS); stageB(p, 2, kS); stageB(p, 3, kS);
        stageA(p, 0, kS); stageA(p, 2, kS);
        __builtin_amdgcn_s_setprio(1);
#pragma unroll
        for (int m = 0; m < 4; ++m)
#pragma unroll
            for (int n = 0; n < 4; ++n)
                acc[4 + m][n] = __builtin_amdgcn_mfma_f32_16x16x32_bf16(ao1[m], bg1[n], acc[4 + m][n], 0, 0, 0);
        __builtin_amdgcn_s_setprio(0);
        // retire A-odd of tile t+1 (staged P1 of t: 3-phase flight)
        asm volatile("s_waitcnt vmcnt(6)" ::: "memory");
        __builtin_amdgcn_s_barrier();
    }
    asm volatile("s_waitcnt vmcnt(0)" ::: "memory");  // drain dummy stages

    // ---- epilogue: D[row][col], col = lane&15, row = (lane>>4)*4 + reg ----
    const int crow0 = brow + wm * 128;
    const int ccol0 = bcol + wn * 64;
    const int rr    = fq * 4;
#pragma unroll
    for (int mh = 0; mh < 2; ++mh) {
#pragma unroll
        for (int m = 0; m < 4; ++m) {
#pragma unroll
            for (int r = 0; r < 4; ++r) {
                const size_t rowoff = (size_t)(crow0 + mh * 64 + m * 16 + rr + r) * NC;
#pragma unroll
                for (int n = 0; n < 4; ++n)
                    C[rowoff + ccol0 + n * 16 + fr] = acc[mh * 4 + m][n][r];
            }
        }
    }
}

// ---------------- fallback path (odd shapes / tiny ws) ----------------

__global__ __launch_bounds__(256) void rnorm_rows(const float* __restrict__ in,
                                                  float* __restrict__ rn, int D) {
    const int row = blockIdx.x;
    float ss = 0.f;
    for (int c = threadIdx.x; c < D; c += 256) {
        const float v = in[(size_t)row * D + c];
        ss += v * v;
    }
#pragma unroll
    for (int off = 32; off > 0; off >>= 1) ss += __shfl_down(ss, off, 64);
    __shared__ float red[4];
    if ((threadIdx.x & 63) == 0) red[threadIdx.x >> 6] = ss;
    __syncthreads();
    if (threadIdx.x == 0) {
        const float tot = red[0] + red[1] + red[2] + red[3];
        rn[row] = 1.0f / fmaxf(sqrtf(tot), EPS_CS);
    }
}

__global__ __launch_bounds__(256) void gemm_f32_fallback(const float* __restrict__ x1,
                                                         const float* __restrict__ x2,
                                                         const float* __restrict__ rn1,
                                                         const float* __restrict__ rn2,
                                                         float* __restrict__ C,
                                                         int NR, int NC, int D) {
    __shared__ float a[16][17], b[16][17];
    const int tx = threadIdx.x & 15, ty = threadIdx.x >> 4;
    const int row = blockIdx.y * 16 + ty;
    const int colb = blockIdx.x * 16;
    float acc = 0.f;
    for (int k0 = 0; k0 < D; k0 += 16) {
        a[ty][tx] = (row < NR && k0 + tx < D) ? x1[(size_t)row * D + k0 + tx] : 0.f;
        b[ty][tx] = (colb + ty < NC && k0 + tx < D) ? x2[(size_t)(colb + ty) * D + k0 + tx] : 0.f;
        __syncthreads();
#pragma unroll
        for (int k = 0; k < 16; ++k) acc += a[ty][k] * b[tx][k];
        __syncthreads();
    }
    if (row < NR && colb + tx < NC)
        C[(size_t)row * NC + colb + tx] = acc * rn1[row] * rn2[colb + tx];
}

// ---------------- launch ----------------

extern "C" void kernel_launch(void* const* d_in, const int* in_sizes, int n_in,
                              void* d_out, int out_size, void* d_ws, size_t ws_size,
                              hipStream_t stream) {
    const float* x1 = (const float*)d_in[0];
    const float* x2 = (const float*)d_in[1];
    float* C = (float*)d_out;

    const int D  = 1024;
    const int NR = in_sizes[0] / D;
    const int NC = in_sizes[1] / D;

    const size_t need = ((size_t)NR + (size_t)NC) * (size_t)D * sizeof(__bf16);
    const bool fast = (in_sizes[0] % D == 0) && (in_sizes[1] % D == 0) &&
                      (NR % BM == 0) && (NC % BN == 0) && (D / BK >= 2) &&
                      (ws_size >= need);

    if (fast) {
        __bf16* An = (__bf16*)d_ws;
        __bf16* Bn = An + (size_t)NR * D;
        nrm_bf16_1024<<<NR, 256, 0, stream>>>(x1, An);
        nrm_bf16_1024<<<NC, 256, 0, stream>>>(x2, Bn);
        const int grid = (NR / BM) * (NC / BN);
        gemm_nt_bf16_256<<<grid, 512, 0, stream>>>(An, Bn, C, NC, D);
    } else {
        float* rn1 = (float*)d_ws;
        float* rn2 = rn1 + NR;
        rnorm_rows<<<NR, 256, 0, stream>>>(x1, rn1, D);
        rnorm_rows<<<NC, 256, 0, stream>>>(x2, rn2, D);
        dim3 g((NC + 15) / 16, (NR + 15) / 16);
        gemm_f32_fallback<<<g, 256, 0, stream>>>(x1, x2, rn1, rn2, C, NR, NC, D);
    }
}